// Round 4
// baseline (924.541 us; speedup 1.0000x reference)
//
#include <hip/hip_runtime.h>

// CNN_pre_LSTM, register-resident design.
// lane = sample; each thread computes its ENTIRE sample pipeline in registers:
//   x(24) -> conv11(1->8)+ReLU -> conv12(8->8)+ReLU -> pool2 -> h2p[8][12]
//         -> conv21(8->16)+ReLU -> conv22(16->16)+ReLU -> pool2 -> h4p[16][6]
//         -> Linear(96->24) -> y[24]
// All weights are wave-uniform -> SGPR (s_load) operands of v_fmac.
// LDS is used ONLY as a coalesce-transpose for input and output.
// No cross-wave data flow, 2 barriers total, conv stages have zero LDS traffic.
// Streaming window liveness keeps VGPR peak ~200 (< 256 = 2 waves/SIMD cap).

#define TPB 256

__launch_bounds__(TPB, 2)   // >=2 waves/EU -> VGPR cap 256
__global__ void cnn_pre_lstm_kernel(
    const float* __restrict__ x,
    const float* __restrict__ w11, const float* __restrict__ b11,
    const float* __restrict__ w12, const float* __restrict__ b12,
    const float* __restrict__ w21, const float* __restrict__ b21,
    const float* __restrict__ w22, const float* __restrict__ b22,
    const float* __restrict__ Wl,  const float* __restrict__ bl,
    float* __restrict__ out)
{
    __shared__ float sIn[TPB * 28];   // [sample][28pad], 28 KB
    __shared__ float sOut[TPB * 25];  // [sample][25pad], 25.6 KB

    const int tid = threadIdx.x;

    // ---- Stage in: coalesced global float4 -> LDS transpose ----------------
    {
        const float4* xg4 = (const float4*)(x + (size_t)blockIdx.x * (TPB * 24));
        #pragma unroll
        for (int q = 0; q < 6; ++q) {
            int o4 = tid + q * TPB;            // 0..1535
            float4 v = xg4[o4];
            int o = o4 * 4, s = o / 24, j = o % 24;   // 24%4==0 -> j..j+3 in-row
            float* r = &sIn[s * 28 + j];
            r[0] = v.x; r[1] = v.y; r[2] = v.z; r[3] = v.w;
        }
    }
    __syncthreads();

    // ---- Per-lane x with zero pads: xv[0]=x[-1]=0, xv[25]=x[24]=0 ----------
    float xv[26];
    xv[0] = 0.f; xv[25] = 0.f;
    #pragma unroll
    for (int q = 0; q < 6; ++q) {
        float4 v = *(const float4*)&sIn[tid * 28 + q * 4];
        xv[1 + q*4 + 0] = v.x; xv[1 + q*4 + 1] = v.y;
        xv[1 + q*4 + 2] = v.z; xv[1 + q*4 + 3] = v.w;
    }

    // ---- Phase A: conv11+ReLU -> conv12+ReLU -> pool2  => h2p[8][12] -------
    float h2p[8][12];
    {
        float h1a[8], h1b[8], h1c[8], po[8];
        #pragma unroll
        for (int c = 0; c < 8; ++c) {
            h1a[c] = 0.f;   // h1 col -1 (pad)
            h1b[c] = fmaxf(fmaf(w11[c*3+0], xv[0],
                           fmaf(w11[c*3+1], xv[1],
                           fmaf(w11[c*3+2], xv[2], b11[c]))), 0.f);  // col 0
        }
        #pragma unroll
        for (int p = 0; p < 24; ++p) {
            // h1 col p+1 (zeros beyond the end)
            #pragma unroll
            for (int c = 0; c < 8; ++c) {
                if (p < 23)
                    h1c[c] = fmaxf(fmaf(w11[c*3+0], xv[p+1],
                                   fmaf(w11[c*3+1], xv[p+2],
                                   fmaf(w11[c*3+2], xv[p+3], b11[c]))), 0.f);
                else
                    h1c[c] = 0.f;
            }
            // conv12 at position p over window (h1a,h1b,h1c)
            float o[8];
            #pragma unroll
            for (int co = 0; co < 8; ++co) {
                float a = b12[co];
                #pragma unroll
                for (int ci = 0; ci < 8; ++ci) {
                    const float* wp = w12 + (co*8 + ci)*3;
                    a = fmaf(wp[0], h1a[ci], fmaf(wp[1], h1b[ci], fmaf(wp[2], h1c[ci], a)));
                }
                o[co] = a;
            }
            if ((p & 1) == 0) {
                #pragma unroll
                for (int co = 0; co < 8; ++co) po[co] = o[co];
            } else {
                #pragma unroll
                for (int co = 0; co < 8; ++co)
                    h2p[co][p >> 1] = fmaxf(fmaxf(po[co], o[co]), 0.f);
            }
            #pragma unroll
            for (int c = 0; c < 8; ++c) { h1a[c] = h1b[c]; h1b[c] = h1c[c]; }
        }
    }

    // ---- Phase B: conv21+ReLU -> conv22+ReLU -> pool2  => h4p[16][6] -------
    float h4p[16][6];
    {
        float h3a[16], h3b[16], h3c[16], pb[16];
        #pragma unroll
        for (int c = 0; c < 16; ++c) {
            h3a[c] = 0.f;   // h3 col -1 (pad)
            float a = b21[c];
            #pragma unroll
            for (int ci = 0; ci < 8; ++ci) {
                const float* wp = w21 + (c*8 + ci)*3;
                // col 0: k=0 hits pad; k=1 -> h2p[*][0]; k=2 -> h2p[*][1]
                a = fmaf(wp[1], h2p[ci][0], fmaf(wp[2], h2p[ci][1], a));
            }
            h3b[c] = fmaxf(a, 0.f);
        }
        #pragma unroll
        for (int p = 0; p < 12; ++p) {
            // h3 col p+1 (zeros beyond the end)
            #pragma unroll
            for (int c = 0; c < 16; ++c) {
                if (p < 11) {
                    float a = b21[c];
                    #pragma unroll
                    for (int ci = 0; ci < 8; ++ci) {
                        const float* wp = w21 + (c*8 + ci)*3;
                        a = fmaf(wp[0], h2p[ci][p], fmaf(wp[1], h2p[ci][p+1], a));
                        if (p + 2 < 12) a = fmaf(wp[2], h2p[ci][p+2], a);
                    }
                    h3c[c] = fmaxf(a, 0.f);
                } else {
                    h3c[c] = 0.f;
                }
            }
            // conv22 at position p over window (h3a,h3b,h3c)
            float o[16];
            #pragma unroll
            for (int co = 0; co < 16; ++co) {
                float a = b22[co];
                #pragma unroll
                for (int ci = 0; ci < 16; ++ci) {
                    const float* wp = w22 + (co*16 + ci)*3;
                    a = fmaf(wp[0], h3a[ci], fmaf(wp[1], h3b[ci], fmaf(wp[2], h3c[ci], a)));
                }
                o[co] = a;
            }
            if ((p & 1) == 0) {
                #pragma unroll
                for (int co = 0; co < 16; ++co) pb[co] = o[co];
            } else {
                #pragma unroll
                for (int co = 0; co < 16; ++co)
                    h4p[co][p >> 1] = fmaxf(fmaxf(pb[co], o[co]), 0.f);
            }
            #pragma unroll
            for (int c = 0; c < 16; ++c) { h3a[c] = h3b[c]; h3b[c] = h3c[c]; }
        }
    }

    // ---- Phase C: Linear 96 -> 24, f = c*6 + p (torch reshape order) -------
    float y[24];
    #pragma unroll
    for (int j = 0; j < 24; ++j) y[j] = bl[j];
    #pragma unroll
    for (int c = 0; c < 16; ++c) {
        #pragma unroll
        for (int p = 0; p < 6; ++p) {
            float v = h4p[c][p];
            const int f = c*6 + p;
            #pragma unroll
            for (int j = 0; j < 24; ++j)
                y[j] = fmaf(Wl[j*96 + f], v, y[j]);   // 24 independent chains
        }
    }

    // ---- Stage out: LDS transpose -> coalesced global float4 ---------------
    #pragma unroll
    for (int j = 0; j < 24; ++j) sOut[tid * 25 + j] = y[j];
    __syncthreads();
    {
        float4* og4 = (float4*)(out + (size_t)blockIdx.x * (TPB * 24));
        #pragma unroll
        for (int q = 0; q < 6; ++q) {
            int o4 = tid + q * TPB;
            int o = o4 * 4, s = o / 24, j = o % 24;
            const float* r = &sOut[s * 25 + j];
            float4 v; v.x = r[0]; v.y = r[1]; v.z = r[2]; v.w = r[3];
            og4[o4] = v;
        }
    }
}

extern "C" void kernel_launch(void* const* d_in, const int* in_sizes, int n_in,
                              void* d_out, int out_size, void* d_ws, size_t ws_size,
                              hipStream_t stream) {
    const float* x   = (const float*)d_in[0];
    const float* w11 = (const float*)d_in[1];
    const float* b11 = (const float*)d_in[2];
    const float* w12 = (const float*)d_in[3];
    const float* b12 = (const float*)d_in[4];
    const float* w21 = (const float*)d_in[5];
    const float* b21 = (const float*)d_in[6];
    const float* w22 = (const float*)d_in[7];
    const float* b22 = (const float*)d_in[8];
    const float* Wl  = (const float*)d_in[9];
    const float* bl  = (const float*)d_in[10];
    float* out = (float*)d_out;

    const int n_samples = in_sizes[0] / 24;    // 131072
    const int blocks = n_samples / TPB;        // 512

    hipLaunchKernelGGL(cnn_pre_lstm_kernel, dim3(blocks), dim3(TPB), 0, stream,
                       x, w11, b11, w12, b12, w21, b21, w22, b22, Wl, bl, out);
}

// Round 5
// 194.750 us; speedup vs baseline: 4.7473x; 4.7473x over previous
//
#include <hip/hip_runtime.h>

// CNN_pre_LSTM — position-split design, v3.
// Block: 256 threads = 4 waves, 64 samples; lane = sample in EVERY stage.
// Waves split conv work by POSITION (not channel): each wave reads a small
// halo window of the input map ONCE into registers, then computes ALL output
// channels from it -> ~18 FMA per ds_read (vs ~5.8 in the channel-split
// version) and zero loop-carried window registers (no v_mov rotation).
// conv11 is fused into conv12 (recomputed per wave; +48 FMA/wave, -48KB LDS
// traffic and -1 barrier). All weights wave-uniform -> s_load operands.
//
// LDS (73.98 KB -> 2 blocks/CU):
//   bufA[12288]: sIn [64][29] (st0-2) | h3 [16][12][64] (st3-4) | sOut [64][25] (st5-6)
//   bufB[6208]:  h2p [64][97] (st2-3) | h4p [64][97] (st4-5)
// Layouts: [ch][pos][64] -> lane-stride-1 (conflict-free); [sample][97|29|25]
// -> odd float stride (2 lanes/bank = free).

#define TPB 256

__launch_bounds__(TPB, 2)
__global__ void cnn_pre_lstm_kernel(
    const float* __restrict__ x,
    const float* __restrict__ w11, const float* __restrict__ b11,
    const float* __restrict__ w12, const float* __restrict__ b12,
    const float* __restrict__ w21, const float* __restrict__ b21,
    const float* __restrict__ w22, const float* __restrict__ b22,
    const float* __restrict__ Wl,  const float* __restrict__ bl,
    float* __restrict__ out)
{
    __shared__ float bufA[12288];
    __shared__ float bufB[6208];

    const int tid = threadIdx.x;
    const int ln  = tid & 63;
    const int wv  = __builtin_amdgcn_readfirstlane(tid >> 6);  // 0..3, uniform

    // ---- Stage 0: coalesced x load -> sIn [64][29], x at col 2+p, zero pads
    {
        const float* xg = x + (size_t)blockIdx.x * 1536;
        #pragma unroll
        for (int k = 0; k < 6; ++k) {
            int o = tid + k * TPB;            // 0..1535
            int s = o / 24, p = o % 24;
            bufA[s * 29 + 2 + p] = xg[o];
        }
        // zero the pad columns {0,1,26,27,28} of each of 64 rows (320 slots)
        #pragma unroll
        for (int z = tid; z < 320; z += TPB) {
            int s = z / 5, which = z % 5;
            int idx = (which < 2) ? which : (24 + which);   // 0,1,26,27,28
            bufA[s * 29 + idx] = 0.f;
        }
    }
    __syncthreads();

    // Edge masks (wave-uniform)
    const float mLo = (wv == 0) ? 0.f : 1.f;   // left boundary owner
    const float mHi = (wv == 3) ? 0.f : 1.f;   // right boundary owner

    // ---- Stage 1+2 fused: conv11+ReLU (regs) -> conv12+ReLU+pool -> h2p ----
    // wave handles conv12 output positions p0..p0+5 (p0 = 6*wv)
    {
        const int p0 = wv * 6;
        float xw[10];                         // x[p0-2 .. p0+7], pads included
        #pragma unroll
        for (int i = 0; i < 10; ++i) xw[i] = bufA[ln * 29 + p0 + i];

        float h1w[8][8];                      // h1[c][q], q = p0-1 .. p0+6
        #pragma unroll
        for (int c = 0; c < 8; ++c) {
            float w0 = w11[c*3+0], w1 = w11[c*3+1], w2 = w11[c*3+2], bb = b11[c];
            #pragma unroll
            for (int i = 0; i < 8; ++i)
                h1w[c][i] = fmaxf(fmaf(w0, xw[i], fmaf(w1, xw[i+1], fmaf(w2, xw[i+2], bb))), 0.f);
            h1w[c][0] *= mLo;                 // q = -1 -> 0
            h1w[c][7] *= mHi;                 // q = 24 -> 0
        }

        #pragma unroll
        for (int co = 0; co < 8; ++co) {
            float acc[6];
            float bb = b12[co];
            #pragma unroll
            for (int p = 0; p < 6; ++p) acc[p] = bb;
            #pragma unroll
            for (int ci = 0; ci < 8; ++ci) {
                const float* wp = w12 + (co*8 + ci)*3;
                float w0 = wp[0], w1 = wp[1], w2 = wp[2];
                #pragma unroll
                for (int p = 0; p < 6; ++p)
                    acc[p] = fmaf(w0, h1w[ci][p], fmaf(w1, h1w[ci][p+1], fmaf(w2, h1w[ci][p+2], acc[p])));
            }
            #pragma unroll
            for (int q = 0; q < 3; ++q)
                bufB[ln*97 + co*12 + 3*wv + q] =
                    fmaxf(fmaxf(acc[2*q], acc[2*q+1]), 0.f);
        }
    }
    __syncthreads();

    // ---- Stage 3: conv21 + ReLU; wave: 3 positions (p0 = 3*wv), all 16 co --
    {
        const int p0 = wv * 3;
        const int pL = (wv == 0) ? 0  : (p0 - 1);   // clamped edge addresses
        const int pR = (wv == 3) ? 11 : (p0 + 3);

        float h2w[8][5];                      // h2p[ci][p0-1 .. p0+3]
        #pragma unroll
        for (int ci = 0; ci < 8; ++ci) {
            h2w[ci][0] = bufB[ln*97 + ci*12 + pL] * mLo;
            #pragma unroll
            for (int i = 1; i < 4; ++i)
                h2w[ci][i] = bufB[ln*97 + ci*12 + p0 - 1 + i];
            h2w[ci][4] = bufB[ln*97 + ci*12 + pR] * mHi;
        }

        #pragma unroll
        for (int co = 0; co < 16; ++co) {
            float a0 = b21[co], a1 = a0, a2 = a0;
            #pragma unroll
            for (int ci = 0; ci < 8; ++ci) {
                const float* wp = w21 + (co*8 + ci)*3;
                float w0 = wp[0], w1 = wp[1], w2 = wp[2];
                a0 = fmaf(w0, h2w[ci][0], fmaf(w1, h2w[ci][1], fmaf(w2, h2w[ci][2], a0)));
                a1 = fmaf(w0, h2w[ci][1], fmaf(w1, h2w[ci][2], fmaf(w2, h2w[ci][3], a1)));
                a2 = fmaf(w0, h2w[ci][2], fmaf(w1, h2w[ci][3], fmaf(w2, h2w[ci][4], a2)));
            }
            bufA[co*768 + (p0 + 0)*64 + ln] = fmaxf(a0, 0.f);
            bufA[co*768 + (p0 + 1)*64 + ln] = fmaxf(a1, 0.f);
            bufA[co*768 + (p0 + 2)*64 + ln] = fmaxf(a2, 0.f);
        }
    }
    __syncthreads();

    // ---- Stage 4: conv22 + ReLU + pool; 2x2 split: wc=co-half, wq=pos-half -
    {
        const int wc = wv & 1, wq = wv >> 1;
        const int co0 = 8 * wc, p0 = 6 * wq;
        const float mL4 = (wq == 0) ? 0.f : 1.f;
        const float mR4 = (wq == 1) ? 0.f : 1.f;
        const int pL = (wq == 0) ? 0  : (p0 - 1);
        const int pR = (wq == 1) ? 11 : (p0 + 6);

        float acc[8][6];
        #pragma unroll
        for (int i = 0; i < 8; ++i) {
            float bb = b22[co0 + i];
            #pragma unroll
            for (int p = 0; p < 6; ++p) acc[i][p] = bb;
        }

        #pragma unroll
        for (int ci = 0; ci < 16; ++ci) {
            float h3w[8];                     // h3[ci][p0-1 .. p0+6]
            h3w[0] = bufA[ci*768 + pL*64 + ln] * mL4;
            #pragma unroll
            for (int i = 1; i < 7; ++i)
                h3w[i] = bufA[ci*768 + (p0 - 1 + i)*64 + ln];
            h3w[7] = bufA[ci*768 + pR*64 + ln] * mR4;

            #pragma unroll
            for (int io = 0; io < 8; ++io) {
                const float* wp = w22 + ((co0 + io)*16 + ci)*3;
                float w0 = wp[0], w1 = wp[1], w2 = wp[2];
                #pragma unroll
                for (int p = 0; p < 6; ++p)
                    acc[io][p] = fmaf(w0, h3w[p], fmaf(w1, h3w[p+1], fmaf(w2, h3w[p+2], acc[io][p])));
            }
        }

        #pragma unroll
        for (int io = 0; io < 8; ++io)
            #pragma unroll
            for (int q = 0; q < 3; ++q)
                bufB[ln*97 + (co0 + io)*6 + 3*wq + q] =
                    fmaxf(fmaxf(acc[io][2*q], acc[io][2*q+1]), 0.f);
    }
    __syncthreads();

    // ---- Stage 5: Linear 96->24; wave computes j0..j0+5 (j0 = 6*wv) --------
    {
        const int j0 = wv * 6;
        float y[6];
        #pragma unroll
        for (int i = 0; i < 6; ++i) y[i] = bl[j0 + i];
        #pragma unroll
        for (int c = 0; c < 16; ++c)
            #pragma unroll
            for (int p = 0; p < 6; ++p) {
                float v = bufB[ln*97 + c*6 + p];
                const int f = c*6 + p;
                #pragma unroll
                for (int i = 0; i < 6; ++i)
                    y[i] = fmaf(Wl[(j0 + i)*96 + f], v, y[i]);
            }
        #pragma unroll
        for (int i = 0; i < 6; ++i)
            bufA[ln*25 + j0 + i] = y[i];
    }
    __syncthreads();

    // ---- Stage 6: coalesced store ------------------------------------------
    {
        float* og = out + (size_t)blockIdx.x * 1536;
        #pragma unroll
        for (int k = 0; k < 6; ++k) {
            int o = tid + k * TPB;
            int s = o / 24, j = o % 24;
            og[o] = bufA[s*25 + j];
        }
    }
}

extern "C" void kernel_launch(void* const* d_in, const int* in_sizes, int n_in,
                              void* d_out, int out_size, void* d_ws, size_t ws_size,
                              hipStream_t stream) {
    const float* x   = (const float*)d_in[0];
    const float* w11 = (const float*)d_in[1];
    const float* b11 = (const float*)d_in[2];
    const float* w12 = (const float*)d_in[3];
    const float* b12 = (const float*)d_in[4];
    const float* w21 = (const float*)d_in[5];
    const float* b21 = (const float*)d_in[6];
    const float* w22 = (const float*)d_in[7];
    const float* b22 = (const float*)d_in[8];
    const float* Wl  = (const float*)d_in[9];
    const float* bl  = (const float*)d_in[10];
    float* out = (float*)d_out;

    const int n_samples = in_sizes[0] / 24;    // 131072
    const int blocks = n_samples / 64;         // 2048

    hipLaunchKernelGGL(cnn_pre_lstm_kernel, dim3(blocks), dim3(TPB), 0, stream,
                       x, w11, b11, w12, b12, w21, b21, w22, b22, Wl, bl, out);
}

// Round 6
// 174.440 us; speedup vs baseline: 5.3000x; 1.1164x over previous
//
#include <hip/hip_runtime.h>
#include <hip/hip_fp16.h>

// CNN_pre_LSTM v4 — R1 channel-split structure + LDS-resident weights.
// Theory: R1/R3/R5 wall time tracks per-wave WEIGHT-stream volume through
// SGPRs (112 regs -> chunked s_loads -> lgkmcnt serialization). Fix: all
// weights live in LDS (broadcast ds_read -> VGPRs, hoistable, no chunking).
// h1/h3 stored fp16 in LDS to fit 2 blocks/CU (24+24+15 KB = 63 KB).
// Block: 256 thr = 4 waves, 64 samples, lane = sample everywhere.

#define TPB 256

// weight offsets in sW (floats)
#define oW11 0
#define oW12 24
#define oW21 216
#define oW22 600
#define oWl  1368
#define oB11 3672
#define oB12 3680
#define oB21 3688
#define oB22 3704
#define oBl  3720

__launch_bounds__(TPB, 2)
__global__ void cnn_pre_lstm_kernel(
    const float* __restrict__ x,
    const float* __restrict__ w11, const float* __restrict__ b11,
    const float* __restrict__ w12, const float* __restrict__ b12,
    const float* __restrict__ w21, const float* __restrict__ b21,
    const float* __restrict__ w22, const float* __restrict__ b22,
    const float* __restrict__ Wl,  const float* __restrict__ bl,
    float* __restrict__ out)
{
    __shared__ __align__(16) __half hA[12288];  // 24 KB: h1 [8][24][64] | h3 [16][12][64] | sOut alias float[64][25]
    __shared__ __align__(16) float  fB[6144];   // 24 KB: sIn [64][25] | h2p [8][12][64] | h4p [16][6][64]
    __shared__ __align__(16) float  sW[3744];   // 14.6 KB: all weights + biases

    const int tid = threadIdx.x;
    const int ln  = tid & 63;
    const int wv  = __builtin_amdgcn_readfirstlane(tid >> 6);  // 0..3

    // ---- Stage 0: preload weights -> LDS (float4 bulk) + x -> LDS ----------
    if (tid < 48)  ((float4*)(sW + oW12))[tid] = ((const float4*)w12)[tid];   // 192 f
    if (tid < 96)  ((float4*)(sW + oW21))[tid] = ((const float4*)w21)[tid];   // 384 f
    if (tid < 192) ((float4*)(sW + oW22))[tid] = ((const float4*)w22)[tid];   // 768 f
    #pragma unroll
    for (int i = tid; i < 576; i += TPB)
        ((float4*)(sW + oWl))[i] = ((const float4*)Wl)[i];                    // 2304 f
    if (tid < 24) sW[oW11 + tid] = w11[tid];
    if (tid < 8)  { sW[oB11 + tid] = b11[tid]; sW[oB12 + tid] = b12[tid]; }
    if (tid < 16) { sW[oB21 + tid] = b21[tid]; sW[oB22 + tid] = b22[tid]; }
    if (tid < 24) sW[oBl + tid] = bl[tid];
    {
        const float* xg = x + (size_t)blockIdx.x * 1536;
        #pragma unroll
        for (int k = 0; k < 6; ++k) {
            int o = tid + k * TPB;            // 0..1535
            int s = o / 24, p = o % 24;
            fB[s * 25 + p] = xg[o];           // sIn [64][25], odd stride
        }
    }
    __syncthreads();

    // ---- Stage 1: conv11 (1->8) + ReLU; wave: co {2w,2w+1}; -> hA fp16 -----
    {
        const int co0 = wv * 2;
        float wA0 = sW[oW11+co0*3+0], wA1 = sW[oW11+co0*3+1], wA2 = sW[oW11+co0*3+2];
        float wB0 = sW[oW11+co0*3+3], wB1 = sW[oW11+co0*3+4], wB2 = sW[oW11+co0*3+5];
        float bA = sW[oB11+co0], bB = sW[oB11+co0+1];

        float xm = 0.f, xc = fB[ln*25 + 0], xp;
        #pragma unroll
        for (int p = 0; p < 24; ++p) {
            xp = (p < 23) ? fB[ln*25 + p + 1] : 0.f;
            float a = fmaf(wA0, xm, fmaf(wA1, xc, fmaf(wA2, xp, bA)));
            float b = fmaf(wB0, xm, fmaf(wB1, xc, fmaf(wB2, xp, bB)));
            hA[ co0      * 1536 + p * 64 + ln] = __float2half(fmaxf(a, 0.f));
            hA[(co0 + 1) * 1536 + p * 64 + ln] = __float2half(fmaxf(b, 0.f));
            xm = xc; xc = xp;
        }
    }
    __syncthreads();

    // ---- Stage 2: conv12 (8->8) + ReLU + pool2 -> h2p (fB fp32) ------------
    {
        const int co0 = wv * 2;
        float acc[2][24];
        {
            float bb0 = sW[oB12+co0], bb1 = sW[oB12+co0+1];
            #pragma unroll
            for (int p = 0; p < 24; ++p) { acc[0][p] = bb0; acc[1][p] = bb1; }
        }
        for (int ci = 0; ci < 8; ++ci) {
            float wg[2][3];
            #pragma unroll
            for (int i = 0; i < 2; ++i)
                #pragma unroll
                for (int k = 0; k < 3; ++k)
                    wg[i][k] = sW[oW12 + (co0 + i)*24 + ci*3 + k];
            const int cb = ci * 1536 + ln;
            float xm = 0.f, xc = __half2float(hA[cb]), xp;
            #pragma unroll
            for (int p = 0; p < 24; ++p) {
                xp = (p < 23) ? __half2float(hA[cb + (p + 1) * 64]) : 0.f;
                #pragma unroll
                for (int i = 0; i < 2; ++i)
                    acc[i][p] = fmaf(wg[i][0], xm, fmaf(wg[i][1], xc, fmaf(wg[i][2], xp, acc[i][p])));
                xm = xc; xc = xp;
            }
        }
        #pragma unroll
        for (int i = 0; i < 2; ++i)
            #pragma unroll
            for (int q = 0; q < 12; ++q)
                fB[(co0 + i) * 768 + q * 64 + ln] =
                    fmaxf(fmaxf(acc[i][2*q], acc[i][2*q+1]), 0.f);
    }
    __syncthreads();

    // ---- Stage 3: conv21 (8->16) + ReLU -> h3 (hA fp16) --------------------
    {
        const int co0 = wv * 4;
        float acc[4][12];
        #pragma unroll
        for (int i = 0; i < 4; ++i) {
            float bb = sW[oB21 + co0 + i];
            #pragma unroll
            for (int p = 0; p < 12; ++p) acc[i][p] = bb;
        }
        for (int ci = 0; ci < 8; ++ci) {
            float wg[4][3];
            #pragma unroll
            for (int i = 0; i < 4; ++i)
                #pragma unroll
                for (int k = 0; k < 3; ++k)
                    wg[i][k] = sW[oW21 + (co0 + i)*24 + ci*3 + k];
            const int cb = ci * 768 + ln;
            float xm = 0.f, xc = fB[cb], xp;
            #pragma unroll
            for (int p = 0; p < 12; ++p) {
                xp = (p < 11) ? fB[cb + (p + 1) * 64] : 0.f;
                #pragma unroll
                for (int i = 0; i < 4; ++i)
                    acc[i][p] = fmaf(wg[i][0], xm, fmaf(wg[i][1], xc, fmaf(wg[i][2], xp, acc[i][p])));
                xm = xc; xc = xp;
            }
        }
        #pragma unroll
        for (int i = 0; i < 4; ++i)
            #pragma unroll
            for (int p = 0; p < 12; ++p)
                hA[(co0 + i) * 768 + p * 64 + ln] = __float2half(fmaxf(acc[i][p], 0.f));
    }
    __syncthreads();

    // ---- Stage 4: conv22 (16->16) + ReLU + pool2 -> h4p (fB fp32) ----------
    {
        const int co0 = wv * 4;
        float acc[4][12];
        #pragma unroll
        for (int i = 0; i < 4; ++i) {
            float bb = sW[oB22 + co0 + i];
            #pragma unroll
            for (int p = 0; p < 12; ++p) acc[i][p] = bb;
        }
        for (int ci = 0; ci < 16; ++ci) {
            float wg[4][3];
            #pragma unroll
            for (int i = 0; i < 4; ++i)
                #pragma unroll
                for (int k = 0; k < 3; ++k)
                    wg[i][k] = sW[oW22 + (co0 + i)*48 + ci*3 + k];
            const int cb = ci * 768 + ln;
            float xm = 0.f, xc = __half2float(hA[cb]), xp;
            #pragma unroll
            for (int p = 0; p < 12; ++p) {
                xp = (p < 11) ? __half2float(hA[cb + (p + 1) * 64]) : 0.f;
                #pragma unroll
                for (int i = 0; i < 4; ++i)
                    acc[i][p] = fmaf(wg[i][0], xm, fmaf(wg[i][1], xc, fmaf(wg[i][2], xp, acc[i][p])));
                xm = xc; xc = xp;
            }
        }
        #pragma unroll
        for (int i = 0; i < 4; ++i)
            #pragma unroll
            for (int q = 0; q < 6; ++q)
                fB[(co0 + i) * 384 + q * 64 + ln] =
                    fmaxf(fmaxf(acc[i][2*q], acc[i][2*q+1]), 0.f);
    }
    __syncthreads();

    // ---- Stage 5: Linear 96->24; hoist h4p to regs, stream Wl rows (b128) --
    {
        const int j0 = wv * 6;
        float v[96];
        #pragma unroll
        for (int c = 0; c < 16; ++c)
            #pragma unroll
            for (int p = 0; p < 6; ++p)
                v[c*6 + p] = fB[c * 384 + p * 64 + ln];   // f = c*6+p (torch order)

        float acc6[6];
        #pragma unroll
        for (int i = 0; i < 6; ++i) acc6[i] = sW[oBl + j0 + i];

        float* sOutF = (float*)hA;                         // region A reuse
        #pragma unroll
        for (int q = 0; q < 24; ++q) {                     // 4 features per step
            #pragma unroll
            for (int i = 0; i < 6; ++i) {
                float4 w4 = ((const float4*)(sW + oWl + (j0 + i) * 96))[q];
                acc6[i] = fmaf(w4.x, v[q*4+0], fmaf(w4.y, v[q*4+1],
                          fmaf(w4.z, v[q*4+2], fmaf(w4.w, v[q*4+3], acc6[i]))));
            }
        }
        #pragma unroll
        for (int i = 0; i < 6; ++i)
            sOutF[ln * 25 + j0 + i] = acc6[i];
    }
    __syncthreads();

    // ---- Stage 6: coalesced store ------------------------------------------
    {
        const float* sOutF = (const float*)hA;
        float* og = out + (size_t)blockIdx.x * 1536;
        #pragma unroll
        for (int k = 0; k < 6; ++k) {
            int o = tid + k * TPB;
            int s = o / 24, j = o % 24;
            og[o] = sOutF[s * 25 + j];
        }
    }
}

extern "C" void kernel_launch(void* const* d_in, const int* in_sizes, int n_in,
                              void* d_out, int out_size, void* d_ws, size_t ws_size,
                              hipStream_t stream) {
    const float* x   = (const float*)d_in[0];
    const float* w11 = (const float*)d_in[1];
    const float* b11 = (const float*)d_in[2];
    const float* w12 = (const float*)d_in[3];
    const float* b12 = (const float*)d_in[4];
    const float* w21 = (const float*)d_in[5];
    const float* b21 = (const float*)d_in[6];
    const float* w22 = (const float*)d_in[7];
    const float* b22 = (const float*)d_in[8];
    const float* Wl  = (const float*)d_in[9];
    const float* bl  = (const float*)d_in[10];
    float* out = (float*)d_out;

    const int n_samples = in_sizes[0] / 24;    // 131072
    const int blocks = n_samples / 64;         // 2048

    hipLaunchKernelGGL(cnn_pre_lstm_kernel, dim3(blocks), dim3(TPB), 0, stream,
                       x, w11, b11, w12, b12, w21, b21, w22, b22, Wl, bl, out);
}

// Round 7
// 138.817 us; speedup vs baseline: 6.6602x; 1.2566x over previous
//
#include <hip/hip_runtime.h>

// CNN_pre_LSTM v6 — fp16 channel-pair packing + v_dot2_f32_f16 (fp32 acc).
// Theory: R1 baseline has ~3000 LDS insts/block (~59us pipe busy @5.8cyc) and
// ~61us VALU busy; both ~60% under the 96us wall. Packing 2 channels per u32
// halves LDS reads AND halves VALU (1 ds_read_b32 -> 1 dot2 = 2 MACs, fp32
// accumulate; f16xf16 products are exact in fp32, so only storage rounding).
// Block: 256 thr = 4 waves, 64 samples, lane = sample everywhere.
// LDS 36KB: A[24KB]: h1p2 [4][24][64] | h3p2 [8][12][64] | sOut f32 [64][25]
//           B[12KB]: sIn f32 [64][25] | h2p2 [4][12][64] | h4p2 [8][6][64]
// All layouts [pair][pos][lane]: lane-stride 1 -> conflict-free.

typedef _Float16 h2v __attribute__((ext_vector_type(2)));

__device__ __forceinline__ float fdot2(h2v a, h2v b, float c) {
    return __builtin_amdgcn_fdot2(a, b, c, false);
}
__device__ __forceinline__ unsigned packh2(float a, float b) {
    h2v p; p.x = (_Float16)a; p.y = (_Float16)b;
    return __builtin_bit_cast(unsigned, p);
}
__device__ __forceinline__ h2v ldh2(unsigned u) {
    return __builtin_bit_cast(h2v, u);
}

#define TPB 256

__launch_bounds__(TPB, 3)   // VGPR cap ~170 (spill-safe); 3 blocks/CU via LDS
__global__ void cnn_pre_lstm_kernel(
    const float* __restrict__ x,
    const float* __restrict__ w11, const float* __restrict__ b11,
    const float* __restrict__ w12, const float* __restrict__ b12,
    const float* __restrict__ w21, const float* __restrict__ b21,
    const float* __restrict__ w22, const float* __restrict__ b22,
    const float* __restrict__ Wl,  const float* __restrict__ bl,
    float* __restrict__ out)
{
    __shared__ unsigned sA_[6144];   // 24 KB
    __shared__ unsigned sB_[3072];   // 12 KB
    float* sInF  = (float*)sB_;
    float* sOutF = (float*)sA_;

    const int tid = threadIdx.x;
    const int ln  = tid & 63;
    const int wv  = __builtin_amdgcn_readfirstlane(tid >> 6);  // 0..3

    // ---- Stage 0: coalesced x -> sIn [64][25] f32 --------------------------
    {
        const float* xg = x + (size_t)blockIdx.x * 1536;
        #pragma unroll
        for (int k = 0; k < 6; ++k) {
            int o = tid + k * TPB;            // 0..1535
            int s = o / 24, p = o % 24;
            sInF[s * 25 + p] = xg[o];
        }
    }
    __syncthreads();

    // ---- Stage 1: conv11 (1->8)+ReLU; wave wv -> ch pair (2wv,2wv+1) -------
    {
        const int c0 = 2 * wv;
        const float wA0 = w11[c0*3+0], wA1 = w11[c0*3+1], wA2 = w11[c0*3+2];
        const float wB0 = w11[c0*3+3], wB1 = w11[c0*3+4], wB2 = w11[c0*3+5];
        const float bA = b11[c0], bB = b11[c0+1];

        float xv[24];
        #pragma unroll
        for (int p = 0; p < 24; ++p) xv[p] = sInF[ln*25 + p];

        #pragma unroll
        for (int p = 0; p < 24; ++p) {
            float a = bA, b = bB;
            if (p > 0)  { a = fmaf(wA0, xv[p-1], a); b = fmaf(wB0, xv[p-1], b); }
            a = fmaf(wA1, xv[p], a);  b = fmaf(wB1, xv[p], b);
            if (p < 23) { a = fmaf(wA2, xv[p+1], a); b = fmaf(wB2, xv[p+1], b); }
            sA_[wv*1536 + p*64 + ln] = packh2(fmaxf(a, 0.f), fmaxf(b, 0.f));
        }
    }
    __syncthreads();

    // ---- Stage 2: conv12 (8->8)+ReLU+pool2; wave wv -> co pair (2wv,2wv+1) -
    {
        const int c0 = 2 * wv;
        h2v wp[2][4][3];                       // [co][cipair][k]
        #pragma unroll
        for (int i = 0; i < 2; ++i)
            #pragma unroll
            for (int cp = 0; cp < 4; ++cp)
                #pragma unroll
                for (int k = 0; k < 3; ++k) {
                    const float* wr = w12 + (c0 + i) * 24;
                    wp[i][cp][k] = ldh2(packh2(wr[(2*cp)*3 + k], wr[(2*cp+1)*3 + k]));
                }
        float acc[2][24];
        {
            const float bb0 = b12[c0], bb1 = b12[c0+1];
            #pragma unroll
            for (int p = 0; p < 24; ++p) { acc[0][p] = bb0; acc[1][p] = bb1; }
        }
        #pragma unroll
        for (int cp = 0; cp < 4; ++cp) {
            h2v xv[24];
            #pragma unroll
            for (int p = 0; p < 24; ++p) xv[p] = ldh2(sA_[cp*1536 + p*64 + ln]);
            #pragma unroll
            for (int p = 0; p < 24; ++p) {
                #pragma unroll
                for (int i = 0; i < 2; ++i) {
                    if (p > 0)  acc[i][p] = fdot2(wp[i][cp][0], xv[p-1], acc[i][p]);
                    acc[i][p] = fdot2(wp[i][cp][1], xv[p], acc[i][p]);
                    if (p < 23) acc[i][p] = fdot2(wp[i][cp][2], xv[p+1], acc[i][p]);
                }
            }
        }
        #pragma unroll
        for (int q = 0; q < 12; ++q) {
            float r0 = fmaxf(fmaxf(acc[0][2*q], acc[0][2*q+1]), 0.f);
            float r1 = fmaxf(fmaxf(acc[1][2*q], acc[1][2*q+1]), 0.f);
            sB_[wv*768 + q*64 + ln] = packh2(r0, r1);
        }
    }
    __syncthreads();

    // ---- Stage 3: conv21 (8->16)+ReLU; wave wv -> co 4wv..4wv+3 ------------
    {
        const int c0 = 4 * wv;
        h2v wp[4][4][3];
        #pragma unroll
        for (int i = 0; i < 4; ++i)
            #pragma unroll
            for (int cp = 0; cp < 4; ++cp)
                #pragma unroll
                for (int k = 0; k < 3; ++k) {
                    const float* wr = w21 + (c0 + i) * 24;
                    wp[i][cp][k] = ldh2(packh2(wr[(2*cp)*3 + k], wr[(2*cp+1)*3 + k]));
                }
        float acc[4][12];
        #pragma unroll
        for (int i = 0; i < 4; ++i) {
            const float bb = b21[c0 + i];
            #pragma unroll
            for (int p = 0; p < 12; ++p) acc[i][p] = bb;
        }
        #pragma unroll
        for (int cp = 0; cp < 4; ++cp) {
            h2v xv[12];
            #pragma unroll
            for (int p = 0; p < 12; ++p) xv[p] = ldh2(sB_[cp*768 + p*64 + ln]);
            #pragma unroll
            for (int p = 0; p < 12; ++p) {
                #pragma unroll
                for (int i = 0; i < 4; ++i) {
                    if (p > 0)  acc[i][p] = fdot2(wp[i][cp][0], xv[p-1], acc[i][p]);
                    acc[i][p] = fdot2(wp[i][cp][1], xv[p], acc[i][p]);
                    if (p < 11) acc[i][p] = fdot2(wp[i][cp][2], xv[p+1], acc[i][p]);
                }
            }
        }
        #pragma unroll
        for (int pr = 0; pr < 2; ++pr)
            #pragma unroll
            for (int p = 0; p < 12; ++p)
                sA_[(2*wv + pr)*768 + p*64 + ln] =
                    packh2(fmaxf(acc[2*pr][p], 0.f), fmaxf(acc[2*pr+1][p], 0.f));
    }
    __syncthreads();

    // ---- Stage 4: conv22 (16->16)+ReLU+pool2; wave wv -> co 4wv..4wv+3 -----
    {
        const int c0 = 4 * wv;
        float acc[4][12];
        #pragma unroll
        for (int i = 0; i < 4; ++i) {
            const float bb = b22[c0 + i];
            #pragma unroll
            for (int p = 0; p < 12; ++p) acc[i][p] = bb;
        }
        #pragma unroll
        for (int hh = 0; hh < 2; ++hh) {       // ci halves: pairs 4hh..4hh+3
            h2v wp[4][4][3];
            #pragma unroll
            for (int i = 0; i < 4; ++i)
                #pragma unroll
                for (int cp = 0; cp < 4; ++cp)
                    #pragma unroll
                    for (int k = 0; k < 3; ++k) {
                        const float* wr = w22 + (c0 + i) * 48;
                        const int ci0 = 2 * (4*hh + cp);
                        wp[i][cp][k] = ldh2(packh2(wr[ci0*3 + k], wr[(ci0+1)*3 + k]));
                    }
            #pragma unroll
            for (int cp = 0; cp < 4; ++cp) {
                const int gcp = 4*hh + cp;
                h2v xv[12];
                #pragma unroll
                for (int p = 0; p < 12; ++p) xv[p] = ldh2(sA_[gcp*768 + p*64 + ln]);
                #pragma unroll
                for (int p = 0; p < 12; ++p) {
                    #pragma unroll
                    for (int i = 0; i < 4; ++i) {
                        if (p > 0)  acc[i][p] = fdot2(wp[i][cp][0], xv[p-1], acc[i][p]);
                        acc[i][p] = fdot2(wp[i][cp][1], xv[p], acc[i][p]);
                        if (p < 11) acc[i][p] = fdot2(wp[i][cp][2], xv[p+1], acc[i][p]);
                    }
                }
            }
        }
        #pragma unroll
        for (int pr = 0; pr < 2; ++pr)
            #pragma unroll
            for (int q = 0; q < 6; ++q) {
                float r0 = fmaxf(fmaxf(acc[2*pr][2*q],   acc[2*pr][2*q+1]),   0.f);
                float r1 = fmaxf(fmaxf(acc[2*pr+1][2*q], acc[2*pr+1][2*q+1]), 0.f);
                sB_[(2*wv + pr)*384 + q*64 + ln] = packh2(r0, r1);
            }
    }
    __syncthreads();

    // ---- Stage 5: Linear 96->24; wave wv -> j0..j0+5 (j0 = 6wv) ------------
    // word (cp,q) holds channels (2cp,2cp+1) at pos q -> features 12cp+q, 12cp+q+6
    {
        const int j0 = 6 * wv;
        float v[96];
        #pragma unroll
        for (int cp = 0; cp < 8; ++cp)
            #pragma unroll
            for (int q = 0; q < 6; ++q) {
                h2v t = ldh2(sB_[cp*384 + q*64 + ln]);
                v[12*cp + q]     = (float)t.x;
                v[12*cp + q + 6] = (float)t.y;
            }
        float acc6[6];
        #pragma unroll
        for (int i = 0; i < 6; ++i) acc6[i] = bl[j0 + i];
        #pragma unroll
        for (int i = 0; i < 6; ++i) {
            const float4* wr = (const float4*)(Wl + (j0 + i) * 96);
            #pragma unroll
            for (int g = 0; g < 24; ++g) {
                float4 w4 = wr[g];
                acc6[i] = fmaf(w4.x, v[4*g+0], fmaf(w4.y, v[4*g+1],
                          fmaf(w4.z, v[4*g+2], fmaf(w4.w, v[4*g+3], acc6[i]))));
            }
        }
        #pragma unroll
        for (int i = 0; i < 6; ++i)
            sOutF[ln*25 + j0 + i] = acc6[i];
    }
    __syncthreads();

    // ---- Stage 6: coalesced store ------------------------------------------
    {
        float* og = out + (size_t)blockIdx.x * 1536;
        #pragma unroll
        for (int k = 0; k < 6; ++k) {
            int o = tid + k * TPB;
            int s = o / 24, j = o % 24;
            og[o] = sOutF[s*25 + j];
        }
    }
}

extern "C" void kernel_launch(void* const* d_in, const int* in_sizes, int n_in,
                              void* d_out, int out_size, void* d_ws, size_t ws_size,
                              hipStream_t stream) {
    const float* x   = (const float*)d_in[0];
    const float* w11 = (const float*)d_in[1];
    const float* b11 = (const float*)d_in[2];
    const float* w12 = (const float*)d_in[3];
    const float* b12 = (const float*)d_in[4];
    const float* w21 = (const float*)d_in[5];
    const float* b21 = (const float*)d_in[6];
    const float* w22 = (const float*)d_in[7];
    const float* b22 = (const float*)d_in[8];
    const float* Wl  = (const float*)d_in[9];
    const float* bl  = (const float*)d_in[10];
    float* out = (float*)d_out;

    const int n_samples = in_sizes[0] / 24;    // 131072
    const int blocks = n_samples / 64;         // 2048

    hipLaunchKernelGGL(cnn_pre_lstm_kernel, dim3(blocks), dim3(TPB), 0, stream,
                       x, w11, b11, w12, b12, w21, b21, w22, b22, Wl, bl, out);
}

// Round 9
// 132.093 us; speedup vs baseline: 6.9992x; 1.0509x over previous
//
#include <hip/hip_runtime.h>

// CNN_pre_LSTM v7 — fp16 pair-packing + v_dot2 + PREPACKED weights + TPB=512.
// R7 (68us) accounting: VALU busy 45.5us vs 20us MAC floor; ~500 insts/thread
// rebuild fp16 weight pairs per block; occupancy 27.8% (2.2 blocks/CU).
// Fixes: (1) one-shot weight-pack kernel into d_ws (conv pairs + Wl pairs) ->
// main kernel s_loads packed words, zero per-block pack VALU; stage5 becomes
// 288 dot2 vs 576 fma + 96 cvt. (2) 512-thr blocks (128 samples): cg=wv&3
// channel group, sh=wv>>2 sample half; 72KB LDS, 2 blocks x 8 waves = 16 w/CU.
// Layouts [pair][pos][sample128]: lane-stride 1, conflict-free.

typedef _Float16 h2v __attribute__((ext_vector_type(2)));

__device__ __forceinline__ float fdot2(h2v a, h2v b, float c) {
    return __builtin_amdgcn_fdot2(a, b, c, false);
}
__device__ __forceinline__ unsigned packh2(float a, float b) {
    h2v p; p.x = (_Float16)a; p.y = (_Float16)b;
    return __builtin_bit_cast(unsigned, p);
}
__device__ __forceinline__ h2v ldh2(unsigned u) {
    return __builtin_bit_cast(h2v, u);
}

// d_ws word offsets
#define W12P 0      // [co8][cp4][k3]   = 96
#define W21P 96     // [co16][cp4][k3]  = 192
#define W22P 288    // [co16][cp8][k3]  = 384
#define WLP  672    // [j24][cp8][q6]   = 1152  (pair = features 12cp+q, 12cp+q+6)
#define NPACK 1824

__global__ void pack_weights_kernel(
    const float* __restrict__ w12, const float* __restrict__ w21,
    const float* __restrict__ w22, const float* __restrict__ Wl,
    unsigned* __restrict__ ws)
{
    for (int i = threadIdx.x; i < NPACK; i += 256) {
        float a, b;
        if (i < W21P) {
            int t = i - W12P, co = t / 12, r = t % 12, cp = r / 3, k = r % 3;
            a = w12[co*24 + (2*cp)*3 + k];  b = w12[co*24 + (2*cp+1)*3 + k];
        } else if (i < W22P) {
            int t = i - W21P, co = t / 12, r = t % 12, cp = r / 3, k = r % 3;
            a = w21[co*24 + (2*cp)*3 + k];  b = w21[co*24 + (2*cp+1)*3 + k];
        } else if (i < WLP) {
            int t = i - W22P, co = t / 24, r = t % 24, cp = r / 3, k = r % 3;
            a = w22[co*48 + (2*cp)*3 + k];  b = w22[co*48 + (2*cp+1)*3 + k];
        } else {
            int t = i - WLP, j = t / 48, r = t % 48, cp = r / 6, q = r % 6;
            a = Wl[j*96 + 12*cp + q];       b = Wl[j*96 + 12*cp + q + 6];
        }
        ws[i] = packh2(a, b);
    }
}

#define TPB 512

__launch_bounds__(TPB, 4)   // 4 waves/EU -> 2 blocks/CU; VGPR cap 128
__global__ void cnn_pre_lstm_kernel(
    const float* __restrict__ x,
    const float* __restrict__ w11, const float* __restrict__ b11,
    const float* __restrict__ b12, const float* __restrict__ b21,
    const float* __restrict__ b22, const float* __restrict__ bl,
    const unsigned* __restrict__ wsp,
    float* __restrict__ out)
{
    __shared__ unsigned sA_[12288];  // 48 KB: h1p2 [4][24][128] | h3p2 [8][12][128] | sOut f32 [128][25]
    __shared__ unsigned sB_[6144];   // 24 KB: sIn f32 [128][25] | h2p2 [4][12][128] | h4p2 [8][6][128]
    float* sInF  = (float*)sB_;
    float* sOutF = (float*)sA_;

    const int tid = threadIdx.x;
    const int ln  = tid & 63;
    const int wv  = __builtin_amdgcn_readfirstlane(tid >> 6);  // 0..7
    const int cg  = wv & 3;          // channel group
    const int ls  = (wv >> 2) * 64 + ln;   // sample 0..127

    // ---- Stage 0: coalesced x -> sIn [128][25] f32 -------------------------
    {
        const float* xg = x + (size_t)blockIdx.x * 3072;
        #pragma unroll
        for (int k = 0; k < 6; ++k) {
            int o = tid + k * TPB;            // 0..3071
            int s = o / 24, p = o % 24;
            sInF[s * 25 + p] = xg[o];
        }
    }
    __syncthreads();

    // ---- Stage 1: conv11 (1->8)+ReLU; (cg) -> ch pair (2cg,2cg+1) ----------
    {
        const int c0 = 2 * cg;
        const float wA0 = w11[c0*3+0], wA1 = w11[c0*3+1], wA2 = w11[c0*3+2];
        const float wB0 = w11[c0*3+3], wB1 = w11[c0*3+4], wB2 = w11[c0*3+5];
        const float bA = b11[c0], bB = b11[c0+1];

        float xv[24];
        #pragma unroll
        for (int p = 0; p < 24; ++p) xv[p] = sInF[ls*25 + p];

        #pragma unroll
        for (int p = 0; p < 24; ++p) {
            float a = bA, b = bB;
            if (p > 0)  { a = fmaf(wA0, xv[p-1], a); b = fmaf(wB0, xv[p-1], b); }
            a = fmaf(wA1, xv[p], a);  b = fmaf(wB1, xv[p], b);
            if (p < 23) { a = fmaf(wA2, xv[p+1], a); b = fmaf(wB2, xv[p+1], b); }
            sA_[cg*3072 + p*128 + ls] = packh2(fmaxf(a, 0.f), fmaxf(b, 0.f));
        }
    }
    __syncthreads();

    // ---- Stage 2: conv12 (8->8)+ReLU+pool2; co pair (2cg,2cg+1) ------------
    {
        const int c0 = 2 * cg;
        h2v wp[2][4][3];
        #pragma unroll
        for (int i = 0; i < 2; ++i)
            #pragma unroll
            for (int cp = 0; cp < 4; ++cp)
                #pragma unroll
                for (int k = 0; k < 3; ++k)
                    wp[i][cp][k] = ldh2(wsp[W12P + (c0+i)*12 + cp*3 + k]);
        float acc[2][24];
        {
            const float bb0 = b12[c0], bb1 = b12[c0+1];
            #pragma unroll
            for (int p = 0; p < 24; ++p) { acc[0][p] = bb0; acc[1][p] = bb1; }
        }
        #pragma unroll
        for (int cp = 0; cp < 4; ++cp) {
            h2v xv[24];
            #pragma unroll
            for (int p = 0; p < 24; ++p) xv[p] = ldh2(sA_[cp*3072 + p*128 + ls]);
            #pragma unroll
            for (int p = 0; p < 24; ++p) {
                #pragma unroll
                for (int i = 0; i < 2; ++i) {
                    if (p > 0)  acc[i][p] = fdot2(wp[i][cp][0], xv[p-1], acc[i][p]);
                    acc[i][p] = fdot2(wp[i][cp][1], xv[p], acc[i][p]);
                    if (p < 23) acc[i][p] = fdot2(wp[i][cp][2], xv[p+1], acc[i][p]);
                }
            }
        }
        #pragma unroll
        for (int q = 0; q < 12; ++q) {
            float r0 = fmaxf(fmaxf(acc[0][2*q], acc[0][2*q+1]), 0.f);
            float r1 = fmaxf(fmaxf(acc[1][2*q], acc[1][2*q+1]), 0.f);
            sB_[cg*1536 + q*128 + ls] = packh2(r0, r1);
        }
    }
    __syncthreads();

    // ---- Stage 3: conv21 (8->16)+ReLU; co 4cg..4cg+3 -----------------------
    {
        const int c0 = 4 * cg;
        h2v wp[4][4][3];
        #pragma unroll
        for (int i = 0; i < 4; ++i)
            #pragma unroll
            for (int cp = 0; cp < 4; ++cp)
                #pragma unroll
                for (int k = 0; k < 3; ++k)
                    wp[i][cp][k] = ldh2(wsp[W21P + (c0+i)*12 + cp*3 + k]);
        float acc[4][12];
        #pragma unroll
        for (int i = 0; i < 4; ++i) {
            const float bb = b21[c0 + i];
            #pragma unroll
            for (int p = 0; p < 12; ++p) acc[i][p] = bb;
        }
        #pragma unroll
        for (int cp = 0; cp < 4; ++cp) {
            h2v xv[12];
            #pragma unroll
            for (int p = 0; p < 12; ++p) xv[p] = ldh2(sB_[cp*1536 + p*128 + ls]);
            #pragma unroll
            for (int p = 0; p < 12; ++p) {
                #pragma unroll
                for (int i = 0; i < 4; ++i) {
                    if (p > 0)  acc[i][p] = fdot2(wp[i][cp][0], xv[p-1], acc[i][p]);
                    acc[i][p] = fdot2(wp[i][cp][1], xv[p], acc[i][p]);
                    if (p < 11) acc[i][p] = fdot2(wp[i][cp][2], xv[p+1], acc[i][p]);
                }
            }
        }
        #pragma unroll
        for (int pr = 0; pr < 2; ++pr)
            #pragma unroll
            for (int p = 0; p < 12; ++p)
                sA_[(2*cg + pr)*1536 + p*128 + ls] =
                    packh2(fmaxf(acc[2*pr][p], 0.f), fmaxf(acc[2*pr+1][p], 0.f));
    }
    __syncthreads();

    // ---- Stage 4: conv22 (16->16)+ReLU+pool2; co 4cg..4cg+3 ----------------
    {
        const int c0 = 4 * cg;
        float acc[4][12];
        #pragma unroll
        for (int i = 0; i < 4; ++i) {
            const float bb = b22[c0 + i];
            #pragma unroll
            for (int p = 0; p < 12; ++p) acc[i][p] = bb;
        }
        #pragma unroll
        for (int hh = 0; hh < 2; ++hh) {
            h2v wp[4][4][3];
            #pragma unroll
            for (int i = 0; i < 4; ++i)
                #pragma unroll
                for (int cp = 0; cp < 4; ++cp)
                    #pragma unroll
                    for (int k = 0; k < 3; ++k)
                        wp[i][cp][k] = ldh2(wsp[W22P + (c0+i)*24 + (4*hh+cp)*3 + k]);
            #pragma unroll
            for (int cp = 0; cp < 4; ++cp) {
                const int gcp = 4*hh + cp;
                h2v xv[12];
                #pragma unroll
                for (int p = 0; p < 12; ++p) xv[p] = ldh2(sA_[gcp*1536 + p*128 + ls]);
                #pragma unroll
                for (int p = 0; p < 12; ++p) {
                    #pragma unroll
                    for (int i = 0; i < 4; ++i) {
                        if (p > 0)  acc[i][p] = fdot2(wp[i][cp][0], xv[p-1], acc[i][p]);
                        acc[i][p] = fdot2(wp[i][cp][1], xv[p], acc[i][p]);
                        if (p < 11) acc[i][p] = fdot2(wp[i][cp][2], xv[p+1], acc[i][p]);
                    }
                }
            }
        }
        #pragma unroll
        for (int pr = 0; pr < 2; ++pr)
            #pragma unroll
            for (int q = 0; q < 6; ++q) {
                float r0 = fmaxf(fmaxf(acc[2*pr][2*q],   acc[2*pr][2*q+1]),   0.f);
                float r1 = fmaxf(fmaxf(acc[2*pr+1][2*q], acc[2*pr+1][2*q+1]), 0.f);
                sB_[(2*cg + pr)*768 + q*128 + ls] = packh2(r0, r1);
            }
    }
    __syncthreads();

    // ---- Stage 5: Linear 96->24 via packed dot2; j0 = 6cg ------------------
    // h4p word (cp,q) = channels (2cp,2cp+1) at pos q = features (12cp+q, 12cp+q+6)
    // Wl packed with the same pairing -> direct dot2.
    {
        const int j0 = 6 * cg;
        h2v hv[8][6];
        #pragma unroll
        for (int cp = 0; cp < 8; ++cp)
            #pragma unroll
            for (int q = 0; q < 6; ++q)
                hv[cp][q] = ldh2(sB_[cp*768 + q*128 + ls]);

        float acc6[6];
        #pragma unroll
        for (int i = 0; i < 6; ++i) acc6[i] = bl[j0 + i];
        #pragma unroll
        for (int i = 0; i < 6; ++i) {
            #pragma unroll
            for (int cp = 0; cp < 8; ++cp) {
                #pragma unroll
                for (int qq = 0; qq < 3; ++qq) {
                    uint2 w2 = *(const uint2*)&wsp[WLP + (j0+i)*48 + cp*6 + 2*qq];
                    acc6[i] = fdot2(ldh2(w2.x), hv[cp][2*qq],   acc6[i]);
                    acc6[i] = fdot2(ldh2(w2.y), hv[cp][2*qq+1], acc6[i]);
                }
            }
        }
        #pragma unroll
        for (int i = 0; i < 6; ++i)
            sOutF[ls*25 + j0 + i] = acc6[i];
    }
    __syncthreads();

    // ---- Stage 6: coalesced store ------------------------------------------
    {
        float* og = out + (size_t)blockIdx.x * 3072;
        #pragma unroll
        for (int k = 0; k < 6; ++k) {
            int o = tid + k * TPB;
            int s = o / 24, j = o % 24;
            og[o] = sOutF[s*25 + j];
        }
    }
}

extern "C" void kernel_launch(void* const* d_in, const int* in_sizes, int n_in,
                              void* d_out, int out_size, void* d_ws, size_t ws_size,
                              hipStream_t stream) {
    const float* x   = (const float*)d_in[0];
    const float* w11 = (const float*)d_in[1];
    const float* b11 = (const float*)d_in[2];
    const float* w12 = (const float*)d_in[3];
    const float* b12 = (const float*)d_in[4];
    const float* w21 = (const float*)d_in[5];
    const float* b21 = (const float*)d_in[6];
    const float* w22 = (const float*)d_in[7];
    const float* b22 = (const float*)d_in[8];
    const float* Wl  = (const float*)d_in[9];
    const float* bl  = (const float*)d_in[10];
    float* out = (float*)d_out;
    unsigned* ws = (unsigned*)d_ws;

    hipLaunchKernelGGL(pack_weights_kernel, dim3(1), dim3(256), 0, stream,
                       w12, w21, w22, Wl, ws);

    const int n_samples = in_sizes[0] / 24;    // 131072
    const int blocks = n_samples / 128;        // 1024

    hipLaunchKernelGGL(cnn_pre_lstm_kernel, dim3(blocks), dim3(TPB), 0, stream,
                       x, w11, b11, b12, b21, b22, bl, ws, out);
}